// Round 8
// baseline (196.611 us; speedup 1.0000x reference)
//
#include <hip/hip_runtime.h>
#include <hip/hip_bf16.h>
#include <math.h>

#define B_     8
#define C_     256
#define HW_    1024
#define NTOT   (B_*C_*HW_)     // 2097152
#define HEADS_ 8
#define DK_    32
#define SCALE_ 0.17677669529663687f  // 32^-0.5

// workspace layout (float offsets)
#define F_STATS 0
#define F_PART  16
#define F_YK2   8192
#define F_YV2   (F_YK2 + NTOT)
#define F_XB    (F_YV2 + NTOT)            // NTOT shorts
#define F_WT    (F_XB + NTOT/2)           // conv w: 1179648 shorts; later wt4 + beta0
#define F_QB    (F_WT + 589824)
#define F_KB    (F_QB + NTOT/2)
#define F_VT    (F_KB + NTOT/2)

typedef float f32x4 __attribute__((ext_vector_type(4)));
typedef short short8 __attribute__((ext_vector_type(8)));

__device__ __forceinline__ short bf16s(float f) {
    __hip_bfloat16 h = __float2bfloat16(f);
    return *(short*)&h;
}
__device__ __forceinline__ unsigned pack_bf16(float a, float b) {
    unsigned ua = (unsigned short)bf16s(a);
    unsigned ub = (unsigned short)bf16s(b);
    return ua | (ub << 16);
}

// ---------------- prep: x -> xb bf16 + LN partial sums (fused) --------------
__global__ void k_prep_x(const float* __restrict__ x, short* __restrict__ xb,
                         float* __restrict__ part) {
    __shared__ short t[64 * 258];
    __shared__ float ls[4], ls2[4];
    int b = blockIdx.x >> 4, p0 = (blockIdx.x & 15) << 6;
    int tid = threadIdx.x;
    float s = 0.f, s2 = 0.f;
    for (int i = tid; i < 256 * 64; i += 256) {
        int ci = i >> 6, p = i & 63;
        float v = x[(b * C_ + ci) * HW_ + p0 + p];
        s += v; s2 += v * v;
        t[p * 258 + ci] = bf16s(v);
    }
    for (int o = 32; o; o >>= 1) { s += __shfl_down(s, o); s2 += __shfl_down(s2, o); }
    int wid = tid >> 6, lane = tid & 63;
    if (lane == 0) { ls[wid] = s; ls2[wid] = s2; }
    __syncthreads();
    if (tid == 0) {
        float a = 0.f, bb = 0.f;
        for (int i = 0; i < 4; i++) { a += ls[i]; bb += ls2[i]; }
        part[blockIdx.x * 2] = a; part[blockIdx.x * 2 + 1] = bb;
    }
    for (int i = tid; i < 64 * 256; i += 256) {
        int p = i >> 8, ci = i & 255;
        xb[(b * HW_ + p0 + p) * C_ + ci] = t[p * 258 + ci];
    }
}

__global__ void k_stats(const float* __restrict__ part, float* __restrict__ stats) {
    __shared__ float ls[256], ls2[256];
    float s = 0.f, s2 = 0.f;
    for (int i = threadIdx.x; i < 128; i += 256) { s += part[2 * i]; s2 += part[2 * i + 1]; }
    ls[threadIdx.x] = s; ls2[threadIdx.x] = s2;
    __syncthreads();
    for (int off = 128; off; off >>= 1) {
        if (threadIdx.x < off) { ls[threadIdx.x] += ls[threadIdx.x + off]; ls2[threadIdx.x] += ls2[threadIdx.x + off]; }
        __syncthreads();
    }
    if (threadIdx.x == 0) {
        float m = ls[0] / (float)NTOT;
        float var = ls2[0] / (float)NTOT - m * m;
        stats[0] = m;
        stats[1] = rsqrtf(var + 1e-5f);
    }
}

// ---------------- prep: conv weights -> wt[tap][n(512)][ci] bf16 ------------
__global__ void k_prep_w(const float* __restrict__ wk, const float* __restrict__ wv,
                         short* __restrict__ wt) {
    int idx = blockIdx.x * 256 + threadIdx.x;
    int ci0 = (idx << 2) & 255;
    int rest = idx >> 6;
    int n = rest & 511, tap = rest >> 9;
    const float* src = (n < 256) ? (wk + (n * C_) * 9) : (wv + ((n - 256) * C_) * 9);
    short4 o;
    short* op = (short*)&o;
    for (int u = 0; u < 4; u++)
        op[u] = bf16s(src[(ci0 + u) * 9 + tap]);
    *(short4*)&wt[((tap * 512 + n) * C_) + ci0] = o;
}

// ---------------- prep: proj weights -> wt4[m][e][c] bf16 (transposed) ------
__global__ void k_prep_pw(const float* __restrict__ Wq, const float* __restrict__ Wk,
                          const float* __restrict__ Wv, const float* __restrict__ Wo,
                          short* __restrict__ wt4) {
    __shared__ short t[64 * 66];
    int mi = blockIdx.x >> 4, tl = blockIdx.x & 15;
    int c0 = (tl >> 2) * 64, e0 = (tl & 3) * 64;
    const float* W = mi == 0 ? Wq : mi == 1 ? Wk : mi == 2 ? Wv : Wo;
    int tid = threadIdx.x;
    for (int i = tid; i < 4096; i += 256) {
        int cl = i >> 6, el = i & 63;
        t[cl * 66 + el] = bf16s(W[(c0 + cl) * 256 + e0 + el]);
    }
    __syncthreads();
    for (int i = tid; i < 4096; i += 256) {
        int el = i >> 6, cl = i & 63;
        wt4[mi * 65536 + (e0 + el) * 256 + c0 + cl] = t[cl * 66 + el];
    }
}

// ---------------- prep: beta0[e] = (bq[e] - m*r*colsum(Wq[:,e])) * SCALE ----
__global__ void k_prep_beta(const float* __restrict__ Wq, const float* __restrict__ bq,
                            const float* __restrict__ stats, float* __restrict__ beta0) {
    __shared__ float ps[1024];
    int t = threadIdx.x, e = t & 255, part = t >> 8;
    float s = 0.f;
    for (int c = part * 64; c < part * 64 + 64; c++) s += Wq[c * 256 + e];
    ps[t] = s;
    __syncthreads();
    if (t < 256) {
        float cs = ps[t] + ps[t + 256] + ps[t + 512] + ps[t + 768];
        beta0[t] = (bq[t] - stats[0] * stats[1] * cs) * SCALE_;
    }
}

// ---------------- conv via MFMA implicit GEMM, deep B pipeline --------------
// grid 512 = b(8) x ptile(16) x ntile(4); block 256 = 4 waves (32px x 64co)
__device__ __forceinline__ int a_off(int slot, int chunk) {
    int c = chunk ^ (slot & 3);
    int s = slot ^ ((slot >> 2) & 1);
    return s * 64 + c * 16;
}

__global__ __launch_bounds__(256, 2)
void k_conv_mfma(const short* __restrict__ xb, const short* __restrict__ wt,
                 const float* __restrict__ bk, const float* __restrict__ bv,
                 float* __restrict__ yk2, float* __restrict__ yv2) {
    __shared__ short a_lds[2][136 * 32];   // double-buffered A tile
    int bid = blockIdx.x;
    int b = bid >> 6, pt = (bid >> 2) & 15, nt = bid & 3;
    int R0 = pt * 2;
    int tid = threadIdx.x;
    int w = tid >> 6, l = tid & 63;
    int wm = w >> 1, wn = w & 1;
    int col16 = l & 15, kq = l >> 4;

    int offs[3], loffs[3];
    #pragma unroll
    for (int it = 0; it < 3; it++) {
        int i = tid + it * 256;
        if (i < 544) {
            int slot = i >> 2, chunk = i & 3;
            int ty = slot / 34, tx = slot - ty * 34;
            int Y = R0 - 1 + ty, X = tx - 1;
            offs[it] = ((unsigned)Y < 32u && (unsigned)X < 32u)
                       ? ((b * HW_ + Y * 32 + X) * C_ + chunk * 8) : -1;
            loffs[it] = a_off(slot, chunk);
        } else { offs[it] = -1; loffs[it] = -1; }
    }

    f32x4 acc[2][4];
    #pragma unroll
    for (int m = 0; m < 2; m++)
        #pragma unroll
        for (int n = 0; n < 4; n++) acc[m][n] = (f32x4)0.f;

    // prologue: stage A step0 into buf 0
    {
        short8 sv[3];
        #pragma unroll
        for (int it = 0; it < 3; it++)
            sv[it] = (offs[it] >= 0) ? *(const short8*)(xb + offs[it]) : (short8)0;
        #pragma unroll
        for (int it = 0; it < 3; it++)
            if (loffs[it] >= 0) *(short8*)((char*)a_lds[0] + loffs[it]) = sv[it];
    }
    __syncthreads();

    const short* wbase = wt + (nt * 128 + wn * 64 + col16) * C_ + kq * 8;

    // B register ring: bb[t] holds tap t of the current step; preload taps 0..7
    short8 bb[9][4];
    #pragma unroll
    for (int t = 0; t < 8; t++)
        #pragma unroll
        for (int nf = 0; nf < 4; nf++)
            bb[t][nf] = *(const short8*)(wbase + (t * 512 + nf * 16) * C_);

    // A-fragment prefetch for step0 tap0
    short8 afc[2];
    #pragma unroll
    for (int mf = 0; mf < 2; mf++) {
        int r = wm * 32 + mf * 16 + col16;
        int slot = (r >> 5) * 34 + (r & 31);
        afc[mf] = *(const short8*)((char*)a_lds[0] + a_off(slot, kq));
    }

    int cur = 0;
    #pragma unroll 1
    for (int step = 0; step < 8; step++) {
        int ci0 = step * 32;
        short8 nv[3];
        if (step < 7) {
            #pragma unroll
            for (int it = 0; it < 3; it++)
                nv[it] = (offs[it] >= 0) ? *(const short8*)(xb + offs[it] + ci0 + 32) : (short8)0;
        }
        const char* abuf = (const char*)a_lds[cur];
        #pragma unroll
        for (int tap = 0; tap < 9; tap++) {
            // prefetch B for gtap+8 into bb[(tap+8)%9]
            {
                const int slot9 = (tap + 8) % 9;          // static per unrolled tap
                const int ntap = (tap == 0) ? 8 : tap - 1; // tap0 -> this step tap8; else next step tap-1
                int nci = (tap == 0) ? ci0 : ci0 + 32;     // step7 tail reads in-bounds garbage, unused
                #pragma unroll
                for (int nf = 0; nf < 4; nf++)
                    bb[slot9][nf] = *(const short8*)(wbase + (ntap * 512 + nf * 16) * C_ + nci);
            }
            // prefetch next tap's A fragments (same buffer)
            short8 afn[2];
            if (tap < 8) {
                const int dyi = (tap + 1) / 3, dxi = (tap + 1) % 3;
                #pragma unroll
                for (int mf = 0; mf < 2; mf++) {
                    int r = wm * 32 + mf * 16 + col16;
                    int slot = ((r >> 5) + dyi) * 34 + (r & 31) + dxi;
                    afn[mf] = *(const short8*)(abuf + a_off(slot, kq));
                }
            }
            #pragma unroll
            for (int mf = 0; mf < 2; mf++)
                #pragma unroll
                for (int nf = 0; nf < 4; nf++)
                    acc[mf][nf] = __builtin_amdgcn_mfma_f32_16x16x32_bf16(afc[mf], bb[tap][nf], acc[mf][nf], 0, 0, 0);
            if (tap < 8) {
                afc[0] = afn[0]; afc[1] = afn[1];
            }
        }
        if (step < 7) {
            #pragma unroll
            for (int it = 0; it < 3; it++)
                if (loffs[it] >= 0) *(short8*)((char*)a_lds[cur ^ 1] + loffs[it]) = nv[it];
            __syncthreads();
            cur ^= 1;
            // prefetch next step tap0 A fragments from the new buffer
            #pragma unroll
            for (int mf = 0; mf < 2; mf++) {
                int r = wm * 32 + mf * 16 + col16;
                int slot = (r >> 5) * 34 + (r & 31);
                afc[mf] = *(const short8*)((char*)a_lds[cur] + a_off(slot, kq));
            }
        }
    }

    const bool isv = (nt >= 2);
    float* dst = isv ? yv2 : yk2;
    const float* bias = isv ? bv : bk;
    int cbase = ((nt & 1) * 128) + wn * 64 + col16;
    #pragma unroll
    for (int nf = 0; nf < 4; nf++) {
        int co = cbase + nf * 16;
        float bi = bias[co];
        #pragma unroll
        for (int mf = 0; mf < 2; mf++) {
            #pragma unroll
            for (int r = 0; r < 4; r++) {
                int pixel = pt * 64 + wm * 32 + mf * 16 + kq * 4 + r;
                dst[(b * HW_ + pixel) * C_ + co] = acc[mf][nf][r] + bi;
            }
        }
    }
}

// ---------------- stage 3: projections via MFMA -----------------------------
__global__ void k_proj_mfma(const short* __restrict__ xb,
                            const float* __restrict__ yk2, const float* __restrict__ yv2,
                            const short* __restrict__ wt4,
                            const float* __restrict__ bkp, const float* __restrict__ bvp,
                            const float* __restrict__ stats, const float* __restrict__ beta0,
                            short* __restrict__ qb, short* __restrict__ kb,
                            short* __restrict__ vt) {
    __shared__ char smem[17408];
    int pj = blockIdx.x, pt = blockIdx.y, b = blockIdx.z;
    int p0 = pt * 32;
    int tid = threadIdx.x, w = tid >> 6, l = tid & 63;
    int c16 = l & 15, kq = l >> 4;

    if (pj == 0) {
        #pragma unroll
        for (int it = 0; it < 4; it++) {
            int i = it * 256 + tid;
            int slab = i >> 7, rem = i & 127, slot = rem >> 2, chunk = rem & 3;
            short8 v = *(const short8*)(xb + ((b * HW_ + p0 + slot) * C_ + slab * 32 + chunk * 8));
            *(short8*)(smem + slab * 2048 + a_off(slot, chunk)) = v;
        }
    } else {
        const float* src = (pj == 1) ? yk2 : yv2;
        #pragma unroll
        for (int it = 0; it < 4; it++) {
            int i = it * 256 + tid;
            int slab = i >> 7, rem = i & 127, slot = rem >> 2, chunk = rem & 3;
            const float* sp = src + (b * HW_ + p0 + slot) * C_ + slab * 32 + chunk * 8;
            float4 f0 = *(const float4*)sp;
            float4 f1 = *(const float4*)(sp + 4);
            short8 v;
            v[0] = bf16s(f0.x); v[1] = bf16s(f0.y); v[2] = bf16s(f0.z); v[3] = bf16s(f0.w);
            v[4] = bf16s(f1.x); v[5] = bf16s(f1.y); v[6] = bf16s(f1.z); v[7] = bf16s(f1.w);
            *(short8*)(smem + slab * 2048 + a_off(slot, chunk)) = v;
        }
    }
    __syncthreads();

    const short* wt_p = wt4 + pj * 65536;
    f32x4 acc[2][4];
    #pragma unroll
    for (int m = 0; m < 2; m++)
        #pragma unroll
        for (int n = 0; n < 4; n++) acc[m][n] = (f32x4)0.f;

    for (int s = 0; s < 8; s++) {
        short8 af[2], bf[4];
        #pragma unroll
        for (int mf = 0; mf < 2; mf++)
            af[mf] = *(const short8*)(smem + s * 2048 + a_off(mf * 16 + c16, kq));
        #pragma unroll
        for (int nf = 0; nf < 4; nf++)
            bf[nf] = *(const short8*)(wt_p + (w * 64 + nf * 16 + c16) * 256 + s * 32 + kq * 8);
        #pragma unroll
        for (int mf = 0; mf < 2; mf++)
            #pragma unroll
            for (int nf = 0; nf < 4; nf++)
                acc[mf][nf] = __builtin_amdgcn_mfma_f32_16x16x32_bf16(af[mf], bf[nf], acc[mf][nf], 0, 0, 0);
    }

    float alpha = (pj == 0) ? stats[1] * SCALE_ : 1.f;
    float beta[4];
    #pragma unroll
    for (int nf = 0; nf < 4; nf++) {
        int e = w * 64 + nf * 16 + c16;
        beta[nf] = (pj == 0) ? beta0[e] : (pj == 1 ? bkp[e] : bvp[e]);
    }
    __syncthreads();

    short* rp = (short*)smem + w * 2176;
    if (pj < 2) {
        #pragma unroll
        for (int mf = 0; mf < 2; mf++)
            #pragma unroll
            for (int nf = 0; nf < 4; nf++)
                #pragma unroll
                for (int rg = 0; rg < 4; rg++) {
                    int px = mf * 16 + kq * 4 + rg, el = nf * 16 + c16;
                    rp[px * 66 + el] = bf16s(alpha * acc[mf][nf][rg] + beta[nf]);
                }
        __syncthreads();
        short* dst = (pj == 0) ? qb : kb;
        #pragma unroll
        for (int j = 0; j < 4; j++) {
            int px = j * 8 + (l >> 3), el = (l & 7) * 8;
            short8 v = *(const short8*)(rp + px * 66 + el);
            int e = w * 64 + el, h = e >> 5, d = e & 31;
            *(short8*)(dst + ((b * 8 + h) * HW_ + p0 + px) * DK_ + d) = v;
        }
    } else {
        #pragma unroll
        for (int mf = 0; mf < 2; mf++)
            #pragma unroll
            for (int nf = 0; nf < 4; nf++)
                #pragma unroll
                for (int rg = 0; rg < 4; rg++) {
                    int px = mf * 16 + kq * 4 + rg, el = nf * 16 + c16;
                    rp[el * 34 + px] = bf16s(acc[mf][nf][rg] + beta[nf]);
                }
        __syncthreads();
        #pragma unroll
        for (int j = 0; j < 4; j++) {
            int el = j * 16 + (l >> 2), px = (l & 3) * 8;
            short8 v = *(const short8*)(rp + el * 34 + px);
            int e = w * 64 + el, h = e >> 5, d = e & 31;
            *(short8*)(vt + ((b * 8 + h) * DK_ + d) * HW_ + p0 + px) = v;
        }
    }
}

// ---------------- stage 4: attention (MFMA flash, swapped QK^T) -------------
__global__ void k_attn(const short* __restrict__ qb, const short* __restrict__ kb,
                       const short* __restrict__ vt, const float* __restrict__ Bb,
                       short* __restrict__ ao) {
    __shared__ __align__(16) short Qs[64 * 32];
    __shared__ __align__(16) short Ks[64 * 32];
    __shared__ __align__(16) short Vs[32 * 64];
    __shared__ __align__(16) short Ps[4][16 * 64];
    int bid = blockIdx.x;
    int h = bid & 7, b = (bid >> 3) & 7, qt = bid >> 6;
    int bh = b * HEADS_ + h;
    int tid = threadIdx.x, w = tid >> 6, l = tid & 63;
    int g = l >> 4, c16 = l & 15;

    *(short8*)(Qs + tid * 8) = *(const short8*)(qb + (bh * HW_ + qt * 64) * DK_ + tid * 8);

    const float* Brow = Bb + (h * HW_ + qt * 64 + w * 16 + c16) * HW_;
    float m_run = -1e30f, l_run = 0.f;
    f32x4 ot[2];
    ot[0] = (f32x4)0.f; ot[1] = (f32x4)0.f;
    char* pbase = (char*)&Ps[w][0];
    int vrow = tid >> 3, vch = tid & 7;

    for (int kv0 = 0; kv0 < HW_; kv0 += 64) {
        __syncthreads();
        *(short8*)(Ks + tid * 8) = *(const short8*)(kb + (bh * HW_ + kv0) * DK_ + tid * 8);
        {
            short8 v = *(const short8*)(vt + (bh * DK_ + vrow) * HW_ + kv0 + vch * 8);
            *(short8*)((char*)Vs + vrow * 128 + ((vch * 16) ^ ((vrow & 7) << 4))) = v;
        }
        __syncthreads();

        short8 qf = *(const short8*)(Qs + (w * 16 + c16) * DK_ + g * 8);
        f32x4 st[4];
        #pragma unroll
        for (int mt = 0; mt < 4; mt++) {
            float4 bi = *(const float4*)(Brow + kv0 + mt * 16 + g * 4);
            f32x4 acc; acc[0] = bi.x; acc[1] = bi.y; acc[2] = bi.z; acc[3] = bi.w;
            short8 kf = *(const short8*)(Ks + (mt * 16 + c16) * DK_ + g * 8);
            st[mt] = __builtin_amdgcn_mfma_f32_16x16x32_bf16(kf, qf, acc, 0, 0, 0);
        }

        float mx = m_run;
        #pragma unroll
        for (int mt = 0; mt < 4; mt++)
            #pragma unroll
            for (int rg = 0; rg < 4; rg++) mx = fmaxf(mx, st[mt][rg]);
        mx = fmaxf(mx, __shfl_xor(mx, 16));
        mx = fmaxf(mx, __shfl_xor(mx, 32));
        float f = __expf(m_run - mx);
        m_run = mx;
        float s = 0.f;
        #pragma unroll
        for (int mt = 0; mt < 4; mt++)
            #pragma unroll
            for (int rg = 0; rg < 4; rg++) {
                float e_ = __expf(st[mt][rg] - mx);
                st[mt][rg] = e_;
                s += e_;
            }
        s += __shfl_xor(s, 16);
        s += __shfl_xor(s, 32);
        l_run = l_run * f + s;

        int fv = __float_as_int(f);
        #pragma unroll
        for (int rg = 0; rg < 4; rg++) {
            float fr = __int_as_float(__builtin_amdgcn_ds_bpermute((g * 4 + rg) << 2, fv));
            ot[0][rg] *= fr;
            ot[1][rg] *= fr;
        }

        #pragma unroll
        for (int mt = 0; mt < 4; mt++) {
            unsigned lo = pack_bf16(st[mt][0], st[mt][1]);
            unsigned hi = pack_bf16(st[mt][2], st[mt][3]);
            unsigned long long pr = (unsigned long long)lo | ((unsigned long long)hi << 32);
            *(unsigned long long*)(pbase + c16 * 128 + ((mt * 32 + g * 8) ^ ((c16 & 7) << 4))) = pr;
        }
        #pragma unroll
        for (int kt = 0; kt < 2; kt++) {
            short8 pf = *(const short8*)(pbase + c16 * 128 + ((kt * 64 + g * 16) ^ ((c16 & 7) << 4)));
            #pragma unroll
            for (int nt = 0; nt < 2; nt++) {
                short8 vf = *(const short8*)((char*)Vs + (c16 + 16 * nt) * 128 + ((kt * 64 + g * 16) ^ ((c16 & 7) << 4)));
                ot[nt] = __builtin_amdgcn_mfma_f32_16x16x32_bf16(pf, vf, ot[nt], 0, 0, 0);
            }
        }
    }

    float linv = 1.f / l_run;
    int lrv = __float_as_int(linv);
    #pragma unroll
    for (int rg = 0; rg < 4; rg++) {
        float li = __int_as_float(__builtin_amdgcn_ds_bpermute((g * 4 + rg) << 2, lrv));
        int qg = qt * 64 + w * 16 + g * 4 + rg;
        #pragma unroll
        for (int nt = 0; nt < 2; nt++)
            ao[(b * HW_ + qg) * C_ + h * DK_ + nt * 16 + c16] = bf16s(ot[nt][rg] * li);
    }
}

// ---------------- stage 5: output projection via MFMA + residual ------------
__global__ void k_out_mfma(const short* __restrict__ aob, const short* __restrict__ wot,
                           const float* __restrict__ bo, const float* __restrict__ x,
                           float* __restrict__ out) {
    __shared__ char smem[16384];
    int pt = blockIdx.x, b = blockIdx.y;
    int p0 = pt * 32;
    int tid = threadIdx.x, w = tid >> 6, l = tid & 63;
    int c16 = l & 15, kq = l >> 4;

    #pragma unroll
    for (int it = 0; it < 4; it++) {
        int i = it * 256 + tid;
        int slab = i >> 7, rem = i & 127, slot = rem >> 2, chunk = rem & 3;
        short8 v = *(const short8*)(aob + ((b * HW_ + p0 + slot) * C_ + slab * 32 + chunk * 8));
        *(short8*)(smem + slab * 2048 + a_off(slot, chunk)) = v;
    }
    __syncthreads();

    f32x4 acc[2][4];
    #pragma unroll
    for (int m = 0; m < 2; m++)
        #pragma unroll
        for (int n = 0; n < 4; n++) acc[m][n] = (f32x4)0.f;

    for (int s = 0; s < 8; s++) {
        short8 af[2], bf[4];
        #pragma unroll
        for (int mf = 0; mf < 2; mf++)
            af[mf] = *(const short8*)(smem + s * 2048 + a_off(mf * 16 + c16, kq));
        #pragma unroll
        for (int nf = 0; nf < 4; nf++)
            bf[nf] = *(const short8*)(wot + (w * 64 + nf * 16 + c16) * 256 + s * 32 + kq * 8);
        #pragma unroll
        for (int mf = 0; mf < 2; mf++)
            #pragma unroll
            for (int nf = 0; nf < 4; nf++)
                acc[mf][nf] = __builtin_amdgcn_mfma_f32_16x16x32_bf16(af[mf], bf[nf], acc[mf][nf], 0, 0, 0);
    }

    #pragma unroll
    for (int nf = 0; nf < 4; nf++) {
        int e = w * 64 + nf * 16 + c16;
        float bov = bo[e];
        #pragma unroll
        for (int mf = 0; mf < 2; mf++) {
            #pragma unroll
            for (int rg = 0; rg < 4; rg++) {
                int px = mf * 16 + kq * 4 + rg;
                int idx = b * (C_ * HW_) + (p0 + px) * 256 + e;
                out[idx] = acc[mf][nf][rg] + bov + x[idx];
            }
        }
    }
}

extern "C" void kernel_launch(void* const* d_in, const int* in_sizes, int n_in,
                              void* d_out, int out_size, void* d_ws, size_t ws_size,
                              hipStream_t stream) {
    const float* x   = (const float*)d_in[0];
    const float* Wq  = (const float*)d_in[1];
    const float* bq  = (const float*)d_in[2];
    const float* ckw = (const float*)d_in[3];
    const float* ckb = (const float*)d_in[4];
    const float* Wk  = (const float*)d_in[5];
    const float* bk  = (const float*)d_in[6];
    const float* cvw = (const float*)d_in[7];
    const float* cvb = (const float*)d_in[8];
    const float* Wv  = (const float*)d_in[9];
    const float* bv  = (const float*)d_in[10];
    const float* Wo  = (const float*)d_in[11];
    const float* bo  = (const float*)d_in[12];
    const float* Bb  = (const float*)d_in[13];
    float* ws  = (float*)d_ws;
    float* out = (float*)d_out;

    short* xb      = (short*)(ws + F_XB);
    short* wt      = (short*)(ws + F_WT);
    short* wt4     = (short*)(ws + F_WT);
    float* beta0   = ws + F_WT + 131072;
    short* qb      = (short*)(ws + F_QB);
    short* kb      = (short*)(ws + F_KB);
    short* vt      = (short*)(ws + F_VT);
    short* aob     = (short*)(ws + F_YK2);
    short* wot     = wt4 + 3 * 65536;

    k_prep_x   <<<128,  256, 0, stream>>>(x, xb, ws + F_PART);
    k_stats    <<<1,    256, 0, stream>>>(ws + F_PART, ws + F_STATS);
    k_prep_w   <<<1152, 256, 0, stream>>>(ckw, cvw, wt);
    k_conv_mfma<<<512,  256, 0, stream>>>(xb, wt, ckb, cvb, ws + F_YK2, ws + F_YV2);
    k_prep_pw  <<<64,   256, 0, stream>>>(Wq, Wk, Wv, Wo, wt4);
    k_prep_beta<<<1,   1024, 0, stream>>>(Wq, bq, ws + F_STATS, beta0);
    k_proj_mfma<<<dim3(3, 32, 8), 256, 0, stream>>>(xb, ws + F_YK2, ws + F_YV2,
                                                    wt4, bk, bv, ws + F_STATS, beta0,
                                                    qb, kb, vt);
    k_attn     <<<1024, 256, 0, stream>>>(qb, kb, vt, Bb, aob);
    k_out_mfma <<<dim3(32, 8), 256, 0, stream>>>(aob, wot, bo, x, out);
}

// Round 9
// 189.869 us; speedup vs baseline: 1.0355x; 1.0355x over previous
//
#include <hip/hip_runtime.h>
#include <hip/hip_bf16.h>
#include <math.h>

#define B_     8
#define C_     256
#define HW_    1024
#define NTOT   (B_*C_*HW_)     // 2097152
#define HEADS_ 8
#define DK_    32
#define SCALE_ 0.17677669529663687f  // 32^-0.5

// workspace layout (float offsets)
#define F_STATS 0
#define F_PART  16
#define F_YK2   8192
#define F_YV2   (F_YK2 + NTOT)
#define F_XB    (F_YV2 + NTOT)            // NTOT shorts
#define F_WT    (F_XB + NTOT/2)           // conv w: 1179648 shorts; later wt4 + beta0
#define F_QB    (F_WT + 589824)
#define F_KB    (F_QB + NTOT/2)
#define F_VT    (F_KB + NTOT/2)

typedef float f32x4 __attribute__((ext_vector_type(4)));
typedef short short8 __attribute__((ext_vector_type(8)));

__device__ __forceinline__ short bf16s(float f) {
    __hip_bfloat16 h = __float2bfloat16(f);
    return *(short*)&h;
}
__device__ __forceinline__ unsigned pack_bf16(float a, float b) {
    unsigned ua = (unsigned short)bf16s(a);
    unsigned ub = (unsigned short)bf16s(b);
    return ua | (ub << 16);
}

// ---------------- prep: x -> xb bf16 + LN partial sums (fused) --------------
__global__ void k_prep_x(const float* __restrict__ x, short* __restrict__ xb,
                         float* __restrict__ part) {
    __shared__ short t[64 * 258];
    __shared__ float ls[4], ls2[4];
    int b = blockIdx.x >> 4, p0 = (blockIdx.x & 15) << 6;
    int tid = threadIdx.x;
    float s = 0.f, s2 = 0.f;
    for (int i = tid; i < 256 * 64; i += 256) {
        int ci = i >> 6, p = i & 63;
        float v = x[(b * C_ + ci) * HW_ + p0 + p];
        s += v; s2 += v * v;
        t[p * 258 + ci] = bf16s(v);
    }
    for (int o = 32; o; o >>= 1) { s += __shfl_down(s, o); s2 += __shfl_down(s2, o); }
    int wid = tid >> 6, lane = tid & 63;
    if (lane == 0) { ls[wid] = s; ls2[wid] = s2; }
    __syncthreads();
    if (tid == 0) {
        float a = 0.f, bb = 0.f;
        for (int i = 0; i < 4; i++) { a += ls[i]; bb += ls2[i]; }
        part[blockIdx.x * 2] = a; part[blockIdx.x * 2 + 1] = bb;
    }
    for (int i = tid; i < 64 * 256; i += 256) {
        int p = i >> 8, ci = i & 255;
        xb[(b * HW_ + p0 + p) * C_ + ci] = t[p * 258 + ci];
    }
}

__global__ void k_stats(const float* __restrict__ part, float* __restrict__ stats) {
    __shared__ float ls[256], ls2[256];
    float s = 0.f, s2 = 0.f;
    for (int i = threadIdx.x; i < 128; i += 256) { s += part[2 * i]; s2 += part[2 * i + 1]; }
    ls[threadIdx.x] = s; ls2[threadIdx.x] = s2;
    __syncthreads();
    for (int off = 128; off; off >>= 1) {
        if (threadIdx.x < off) { ls[threadIdx.x] += ls[threadIdx.x + off]; ls2[threadIdx.x] += ls2[threadIdx.x + off]; }
        __syncthreads();
    }
    if (threadIdx.x == 0) {
        float m = ls[0] / (float)NTOT;
        float var = ls2[0] / (float)NTOT - m * m;
        stats[0] = m;
        stats[1] = rsqrtf(var + 1e-5f);
    }
}

// ---------------- prep: conv weights -> wt[tap][n(512)][ci] bf16 ------------
__global__ void k_prep_w(const float* __restrict__ wk, const float* __restrict__ wv,
                         short* __restrict__ wt) {
    int idx = blockIdx.x * 256 + threadIdx.x;
    int ci0 = (idx << 2) & 255;
    int rest = idx >> 6;
    int n = rest & 511, tap = rest >> 9;
    const float* src = (n < 256) ? (wk + (n * C_) * 9) : (wv + ((n - 256) * C_) * 9);
    short4 o;
    short* op = (short*)&o;
    for (int u = 0; u < 4; u++)
        op[u] = bf16s(src[(ci0 + u) * 9 + tap]);
    *(short4*)&wt[((tap * 512 + n) * C_) + ci0] = o;
}

// ---------------- prep: proj weights -> wt4[m][e][c] bf16 (transposed) ------
__global__ void k_prep_pw(const float* __restrict__ Wq, const float* __restrict__ Wk,
                          const float* __restrict__ Wv, const float* __restrict__ Wo,
                          short* __restrict__ wt4) {
    __shared__ short t[64 * 66];
    int mi = blockIdx.x >> 4, tl = blockIdx.x & 15;
    int c0 = (tl >> 2) * 64, e0 = (tl & 3) * 64;
    const float* W = mi == 0 ? Wq : mi == 1 ? Wk : mi == 2 ? Wv : Wo;
    int tid = threadIdx.x;
    for (int i = tid; i < 4096; i += 256) {
        int cl = i >> 6, el = i & 63;
        t[cl * 66 + el] = bf16s(W[(c0 + cl) * 256 + e0 + el]);
    }
    __syncthreads();
    for (int i = tid; i < 4096; i += 256) {
        int el = i >> 6, cl = i & 63;
        wt4[mi * 65536 + (e0 + el) * 256 + c0 + cl] = t[cl * 66 + el];
    }
}

// ---------------- prep: beta0[e] = (bq[e] - m*r*colsum(Wq[:,e])) * SCALE ----
__global__ void k_prep_beta(const float* __restrict__ Wq, const float* __restrict__ bq,
                            const float* __restrict__ stats, float* __restrict__ beta0) {
    __shared__ float ps[1024];
    int t = threadIdx.x, e = t & 255, part = t >> 8;
    float s = 0.f;
    for (int c = part * 64; c < part * 64 + 64; c++) s += Wq[c * 256 + e];
    ps[t] = s;
    __syncthreads();
    if (t < 256) {
        float cs = ps[t] + ps[t + 256] + ps[t + 512] + ps[t + 768];
        beta0[t] = (bq[t] - stats[0] * stats[1] * cs) * SCALE_;
    }
}

// ---------------- conv via MFMA implicit GEMM, high-TLP tiling --------------
// grid 512 = b(8) x pt(8: 4 image rows = 128px) x nt(8: 64 cols), nt in LOW bits
// block 512 = 8 waves; wave w: wm=w>>1 (image row), wn=w&1 (32-col half)
__device__ __forceinline__ int a_off(int slot, int chunk) {
    int c = chunk ^ (slot & 3);
    int s = slot ^ ((slot >> 2) & 1);
    return s * 64 + c * 16;
}

__global__ __launch_bounds__(512, 4)
void k_conv_mfma(const short* __restrict__ xb, const short* __restrict__ wt,
                 const float* __restrict__ bk, const float* __restrict__ bv,
                 float* __restrict__ yk2, float* __restrict__ yv2) {
    __shared__ short a_lds[2][204 * 32];   // 6 rows x 34 cols x 32 ci, dbuf
    int bid = blockIdx.x;
    int nt = bid & 7, pt = (bid >> 3) & 7, b = bid >> 6;
    int R0 = pt * 4;
    int tid = threadIdx.x;
    int w = tid >> 6, l = tid & 63;
    int wm = w >> 1, wn = w & 1;
    int col16 = l & 15, kq = l >> 4;

    // staging: 816 items (204 slots x 4 chunks); thread does items tid, tid+512
    int offs[2], loffs[2];
    #pragma unroll
    for (int it = 0; it < 2; it++) {
        int i = tid + it * 512;
        if (i < 816) {
            int slot = i >> 2, chunk = i & 3;
            int ty = slot / 34, tx = slot - ty * 34;
            int Y = R0 - 1 + ty, X = tx - 1;
            offs[it] = ((unsigned)Y < 32u && (unsigned)X < 32u)
                       ? ((b * HW_ + Y * 32 + X) * C_ + chunk * 8) : -1;
            loffs[it] = a_off(slot, chunk);
        } else { offs[it] = -1; loffs[it] = -1; }
    }

    f32x4 acc[2][2];
    #pragma unroll
    for (int m = 0; m < 2; m++)
        #pragma unroll
        for (int n = 0; n < 2; n++) acc[m][n] = (f32x4)0.f;

    // prologue: stage step0 into buf 0
    {
        short8 sv[2];
        #pragma unroll
        for (int it = 0; it < 2; it++)
            sv[it] = (offs[it] >= 0) ? *(const short8*)(xb + offs[it]) : (short8)0;
        #pragma unroll
        for (int it = 0; it < 2; it++)
            if (loffs[it] >= 0) *(short8*)((char*)a_lds[0] + loffs[it]) = sv[it];
    }
    __syncthreads();

    const short* wbase = wt + (nt * 64 + wn * 32 + col16) * C_ + kq * 8;
    // 1-ahead B prefetch: bcur = (tap0, step0)
    short8 bcur[2];
    #pragma unroll
    for (int nf = 0; nf < 2; nf++)
        bcur[nf] = *(const short8*)(wbase + (nf * 16) * C_);

    int cur = 0;
    for (int step = 0; step < 8; step++) {
        int ci0 = step * 32;
        short8 nv[2];
        if (step < 7) {
            #pragma unroll
            for (int it = 0; it < 2; it++)
                nv[it] = (offs[it] >= 0) ? *(const short8*)(xb + offs[it] + ci0 + 32) : (short8)0;
        }
        const char* abuf = (const char*)a_lds[cur];
        #pragma unroll
        for (int tap = 0; tap < 9; tap++) {
            short8 bnxt[2];
            {
                int ntap = (tap == 8) ? 0 : tap + 1;
                int nci = (tap == 8) ? ci0 + 32 : ci0;   // step7 tail in-bounds garbage, unused
                #pragma unroll
                for (int nf = 0; nf < 2; nf++)
                    bnxt[nf] = *(const short8*)(wbase + (ntap * 512 + nf * 16) * C_ + nci);
            }
            const int dyi = tap / 3, dxi = tap % 3;
            short8 af[2];
            #pragma unroll
            for (int mf = 0; mf < 2; mf++) {
                int slot = (wm + dyi) * 34 + mf * 16 + col16 + dxi;
                af[mf] = *(const short8*)(abuf + a_off(slot, kq));
            }
            #pragma unroll
            for (int mf = 0; mf < 2; mf++)
                #pragma unroll
                for (int nf = 0; nf < 2; nf++)
                    acc[mf][nf] = __builtin_amdgcn_mfma_f32_16x16x32_bf16(af[mf], bcur[nf], acc[mf][nf], 0, 0, 0);
            bcur[0] = bnxt[0]; bcur[1] = bnxt[1];
        }
        if (step < 7) {
            #pragma unroll
            for (int it = 0; it < 2; it++)
                if (loffs[it] >= 0) *(short8*)((char*)a_lds[cur ^ 1] + loffs[it]) = nv[it];
            __syncthreads();
            cur ^= 1;
        }
    }

    const bool isv = (nt >= 4);
    float* dst = isv ? yv2 : yk2;
    const float* bias = isv ? bv : bk;
    int cbase = (nt & 3) * 64 + wn * 32 + col16;
    #pragma unroll
    for (int nf = 0; nf < 2; nf++) {
        int co = cbase + nf * 16;
        float bi = bias[co];
        #pragma unroll
        for (int mf = 0; mf < 2; mf++) {
            #pragma unroll
            for (int r = 0; r < 4; r++) {
                int pixel = pt * 128 + wm * 32 + mf * 16 + kq * 4 + r;
                dst[(b * HW_ + pixel) * C_ + co] = acc[mf][nf][r] + bi;
            }
        }
    }
}

// ---------------- stage 3: projections via MFMA -----------------------------
__global__ void k_proj_mfma(const short* __restrict__ xb,
                            const float* __restrict__ yk2, const float* __restrict__ yv2,
                            const short* __restrict__ wt4,
                            const float* __restrict__ bkp, const float* __restrict__ bvp,
                            const float* __restrict__ stats, const float* __restrict__ beta0,
                            short* __restrict__ qb, short* __restrict__ kb,
                            short* __restrict__ vt) {
    __shared__ char smem[17408];
    int pj = blockIdx.x, pt = blockIdx.y, b = blockIdx.z;
    int p0 = pt * 32;
    int tid = threadIdx.x, w = tid >> 6, l = tid & 63;
    int c16 = l & 15, kq = l >> 4;

    if (pj == 0) {
        #pragma unroll
        for (int it = 0; it < 4; it++) {
            int i = it * 256 + tid;
            int slab = i >> 7, rem = i & 127, slot = rem >> 2, chunk = rem & 3;
            short8 v = *(const short8*)(xb + ((b * HW_ + p0 + slot) * C_ + slab * 32 + chunk * 8));
            *(short8*)(smem + slab * 2048 + a_off(slot, chunk)) = v;
        }
    } else {
        const float* src = (pj == 1) ? yk2 : yv2;
        #pragma unroll
        for (int it = 0; it < 4; it++) {
            int i = it * 256 + tid;
            int slab = i >> 7, rem = i & 127, slot = rem >> 2, chunk = rem & 3;
            const float* sp = src + (b * HW_ + p0 + slot) * C_ + slab * 32 + chunk * 8;
            float4 f0 = *(const float4*)sp;
            float4 f1 = *(const float4*)(sp + 4);
            short8 v;
            v[0] = bf16s(f0.x); v[1] = bf16s(f0.y); v[2] = bf16s(f0.z); v[3] = bf16s(f0.w);
            v[4] = bf16s(f1.x); v[5] = bf16s(f1.y); v[6] = bf16s(f1.z); v[7] = bf16s(f1.w);
            *(short8*)(smem + slab * 2048 + a_off(slot, chunk)) = v;
        }
    }
    __syncthreads();

    const short* wt_p = wt4 + pj * 65536;
    f32x4 acc[2][4];
    #pragma unroll
    for (int m = 0; m < 2; m++)
        #pragma unroll
        for (int n = 0; n < 4; n++) acc[m][n] = (f32x4)0.f;

    for (int s = 0; s < 8; s++) {
        short8 af[2], bf[4];
        #pragma unroll
        for (int mf = 0; mf < 2; mf++)
            af[mf] = *(const short8*)(smem + s * 2048 + a_off(mf * 16 + c16, kq));
        #pragma unroll
        for (int nf = 0; nf < 4; nf++)
            bf[nf] = *(const short8*)(wt_p + (w * 64 + nf * 16 + c16) * 256 + s * 32 + kq * 8);
        #pragma unroll
        for (int mf = 0; mf < 2; mf++)
            #pragma unroll
            for (int nf = 0; nf < 4; nf++)
                acc[mf][nf] = __builtin_amdgcn_mfma_f32_16x16x32_bf16(af[mf], bf[nf], acc[mf][nf], 0, 0, 0);
    }

    float alpha = (pj == 0) ? stats[1] * SCALE_ : 1.f;
    float beta[4];
    #pragma unroll
    for (int nf = 0; nf < 4; nf++) {
        int e = w * 64 + nf * 16 + c16;
        beta[nf] = (pj == 0) ? beta0[e] : (pj == 1 ? bkp[e] : bvp[e]);
    }
    __syncthreads();

    short* rp = (short*)smem + w * 2176;
    if (pj < 2) {
        #pragma unroll
        for (int mf = 0; mf < 2; mf++)
            #pragma unroll
            for (int nf = 0; nf < 4; nf++)
                #pragma unroll
                for (int rg = 0; rg < 4; rg++) {
                    int px = mf * 16 + kq * 4 + rg, el = nf * 16 + c16;
                    rp[px * 66 + el] = bf16s(alpha * acc[mf][nf][rg] + beta[nf]);
                }
        __syncthreads();
        short* dst = (pj == 0) ? qb : kb;
        #pragma unroll
        for (int j = 0; j < 4; j++) {
            int px = j * 8 + (l >> 3), el = (l & 7) * 8;
            short8 v = *(const short8*)(rp + px * 66 + el);
            int e = w * 64 + el, h = e >> 5, d = e & 31;
            *(short8*)(dst + ((b * 8 + h) * HW_ + p0 + px) * DK_ + d) = v;
        }
    } else {
        #pragma unroll
        for (int mf = 0; mf < 2; mf++)
            #pragma unroll
            for (int nf = 0; nf < 4; nf++)
                #pragma unroll
                for (int rg = 0; rg < 4; rg++) {
                    int px = mf * 16 + kq * 4 + rg, el = nf * 16 + c16;
                    rp[el * 34 + px] = bf16s(acc[mf][nf][rg] + beta[nf]);
                }
        __syncthreads();
        #pragma unroll
        for (int j = 0; j < 4; j++) {
            int el = j * 16 + (l >> 2), px = (l & 3) * 8;
            short8 v = *(const short8*)(rp + el * 34 + px);
            int e = w * 64 + el, h = e >> 5, d = e & 31;
            *(short8*)(vt + ((b * 8 + h) * DK_ + d) * HW_ + p0 + px) = v;
        }
    }
}

// ---------------- stage 4: attention (MFMA flash, swapped QK^T) -------------
__global__ void k_attn(const short* __restrict__ qb, const short* __restrict__ kb,
                       const short* __restrict__ vt, const float* __restrict__ Bb,
                       short* __restrict__ ao) {
    __shared__ __align__(16) short Qs[64 * 32];
    __shared__ __align__(16) short Ks[64 * 32];
    __shared__ __align__(16) short Vs[32 * 64];
    __shared__ __align__(16) short Ps[4][16 * 64];
    int bid = blockIdx.x;
    int h = bid & 7, b = (bid >> 3) & 7, qt = bid >> 6;
    int bh = b * HEADS_ + h;
    int tid = threadIdx.x, w = tid >> 6, l = tid & 63;
    int g = l >> 4, c16 = l & 15;

    *(short8*)(Qs + tid * 8) = *(const short8*)(qb + (bh * HW_ + qt * 64) * DK_ + tid * 8);

    const float* Brow = Bb + (h * HW_ + qt * 64 + w * 16 + c16) * HW_;
    float m_run = -1e30f, l_run = 0.f;
    f32x4 ot[2];
    ot[0] = (f32x4)0.f; ot[1] = (f32x4)0.f;
    char* pbase = (char*)&Ps[w][0];
    int vrow = tid >> 3, vch = tid & 7;

    for (int kv0 = 0; kv0 < HW_; kv0 += 64) {
        __syncthreads();
        *(short8*)(Ks + tid * 8) = *(const short8*)(kb + (bh * HW_ + kv0) * DK_ + tid * 8);
        {
            short8 v = *(const short8*)(vt + (bh * DK_ + vrow) * HW_ + kv0 + vch * 8);
            *(short8*)((char*)Vs + vrow * 128 + ((vch * 16) ^ ((vrow & 7) << 4))) = v;
        }
        __syncthreads();

        short8 qf = *(const short8*)(Qs + (w * 16 + c16) * DK_ + g * 8);
        f32x4 st[4];
        #pragma unroll
        for (int mt = 0; mt < 4; mt++) {
            float4 bi = *(const float4*)(Brow + kv0 + mt * 16 + g * 4);
            f32x4 acc; acc[0] = bi.x; acc[1] = bi.y; acc[2] = bi.z; acc[3] = bi.w;
            short8 kf = *(const short8*)(Ks + (mt * 16 + c16) * DK_ + g * 8);
            st[mt] = __builtin_amdgcn_mfma_f32_16x16x32_bf16(kf, qf, acc, 0, 0, 0);
        }

        float mx = m_run;
        #pragma unroll
        for (int mt = 0; mt < 4; mt++)
            #pragma unroll
            for (int rg = 0; rg < 4; rg++) mx = fmaxf(mx, st[mt][rg]);
        mx = fmaxf(mx, __shfl_xor(mx, 16));
        mx = fmaxf(mx, __shfl_xor(mx, 32));
        float f = __expf(m_run - mx);
        m_run = mx;
        float s = 0.f;
        #pragma unroll
        for (int mt = 0; mt < 4; mt++)
            #pragma unroll
            for (int rg = 0; rg < 4; rg++) {
                float e_ = __expf(st[mt][rg] - mx);
                st[mt][rg] = e_;
                s += e_;
            }
        s += __shfl_xor(s, 16);
        s += __shfl_xor(s, 32);
        l_run = l_run * f + s;

        int fv = __float_as_int(f);
        #pragma unroll
        for (int rg = 0; rg < 4; rg++) {
            float fr = __int_as_float(__builtin_amdgcn_ds_bpermute((g * 4 + rg) << 2, fv));
            ot[0][rg] *= fr;
            ot[1][rg] *= fr;
        }

        #pragma unroll
        for (int mt = 0; mt < 4; mt++) {
            unsigned lo = pack_bf16(st[mt][0], st[mt][1]);
            unsigned hi = pack_bf16(st[mt][2], st[mt][3]);
            unsigned long long pr = (unsigned long long)lo | ((unsigned long long)hi << 32);
            *(unsigned long long*)(pbase + c16 * 128 + ((mt * 32 + g * 8) ^ ((c16 & 7) << 4))) = pr;
        }
        #pragma unroll
        for (int kt = 0; kt < 2; kt++) {
            short8 pf = *(const short8*)(pbase + c16 * 128 + ((kt * 64 + g * 16) ^ ((c16 & 7) << 4)));
            #pragma unroll
            for (int nt = 0; nt < 2; nt++) {
                short8 vf = *(const short8*)((char*)Vs + (c16 + 16 * nt) * 128 + ((kt * 64 + g * 16) ^ ((c16 & 7) << 4)));
                ot[nt] = __builtin_amdgcn_mfma_f32_16x16x32_bf16(pf, vf, ot[nt], 0, 0, 0);
            }
        }
    }

    float linv = 1.f / l_run;
    int lrv = __float_as_int(linv);
    #pragma unroll
    for (int rg = 0; rg < 4; rg++) {
        float li = __int_as_float(__builtin_amdgcn_ds_bpermute((g * 4 + rg) << 2, lrv));
        int qg = qt * 64 + w * 16 + g * 4 + rg;
        #pragma unroll
        for (int nt = 0; nt < 2; nt++)
            ao[(b * HW_ + qg) * C_ + h * DK_ + nt * 16 + c16] = bf16s(ot[nt][rg] * li);
    }
}

// ---------------- stage 5: output projection via MFMA + residual ------------
__global__ void k_out_mfma(const short* __restrict__ aob, const short* __restrict__ wot,
                           const float* __restrict__ bo, const float* __restrict__ x,
                           float* __restrict__ out) {
    __shared__ char smem[16384];
    int pt = blockIdx.x, b = blockIdx.y;
    int p0 = pt * 32;
    int tid = threadIdx.x, w = tid >> 6, l = tid & 63;
    int c16 = l & 15, kq = l >> 4;

    #pragma unroll
    for (int it = 0; it < 4; it++) {
        int i = it * 256 + tid;
        int slab = i >> 7, rem = i & 127, slot = rem >> 2, chunk = rem & 3;
        short8 v = *(const short8*)(aob + ((b * HW_ + p0 + slot) * C_ + slab * 32 + chunk * 8));
        *(short8*)(smem + slab * 2048 + a_off(slot, chunk)) = v;
    }
    __syncthreads();

    f32x4 acc[2][4];
    #pragma unroll
    for (int m = 0; m < 2; m++)
        #pragma unroll
        for (int n = 0; n < 4; n++) acc[m][n] = (f32x4)0.f;

    for (int s = 0; s < 8; s++) {
        short8 af[2], bf[4];
        #pragma unroll
        for (int mf = 0; mf < 2; mf++)
            af[mf] = *(const short8*)(smem + s * 2048 + a_off(mf * 16 + c16, kq));
        #pragma unroll
        for (int nf = 0; nf < 4; nf++)
            bf[nf] = *(const short8*)(wot + (w * 64 + nf * 16 + c16) * 256 + s * 32 + kq * 8);
        #pragma unroll
        for (int mf = 0; mf < 2; mf++)
            #pragma unroll
            for (int nf = 0; nf < 4; nf++)
                acc[mf][nf] = __builtin_amdgcn_mfma_f32_16x16x32_bf16(af[mf], bf[nf], acc[mf][nf], 0, 0, 0);
    }

    #pragma unroll
    for (int nf = 0; nf < 4; nf++) {
        int e = w * 64 + nf * 16 + c16;
        float bov = bo[e];
        #pragma unroll
        for (int mf = 0; mf < 2; mf++) {
            #pragma unroll
            for (int rg = 0; rg < 4; rg++) {
                int px = mf * 16 + kq * 4 + rg;
                int idx = b * (C_ * HW_) + (p0 + px) * 256 + e;
                out[idx] = acc[mf][nf][rg] + bov + x[idx];
            }
        }
    }
}

extern "C" void kernel_launch(void* const* d_in, const int* in_sizes, int n_in,
                              void* d_out, int out_size, void* d_ws, size_t ws_size,
                              hipStream_t stream) {
    const float* x   = (const float*)d_in[0];
    const float* Wq  = (const float*)d_in[1];
    const float* bq  = (const float*)d_in[2];
    const float* ckw = (const float*)d_in[3];
    const float* ckb = (const float*)d_in[4];
    const float* Wk  = (const float*)d_in[5];
    const float* bk  = (const float*)d_in[6];
    const float* cvw = (const float*)d_in[7];
    const float* cvb = (const float*)d_in[8];
    const float* Wv  = (const float*)d_in[9];
    const float* bv  = (const float*)d_in[10];
    const float* Wo  = (const float*)d_in[11];
    const float* bo  = (const float*)d_in[12];
    const float* Bb  = (const float*)d_in[13];
    float* ws  = (float*)d_ws;
    float* out = (float*)d_out;

    short* xb      = (short*)(ws + F_XB);
    short* wt      = (short*)(ws + F_WT);
    short* wt4     = (short*)(ws + F_WT);
    float* beta0   = ws + F_WT + 131072;
    short* qb      = (short*)(ws + F_QB);
    short* kb      = (short*)(ws + F_KB);
    short* vt      = (short*)(ws + F_VT);
    short* aob     = (short*)(ws + F_YK2);
    short* wot     = wt4 + 3 * 65536;

    k_prep_x   <<<128,  256, 0, stream>>>(x, xb, ws + F_PART);
    k_stats    <<<1,    256, 0, stream>>>(ws + F_PART, ws + F_STATS);
    k_prep_w   <<<1152, 256, 0, stream>>>(ckw, cvw, wt);
    k_conv_mfma<<<512,  512, 0, stream>>>(xb, wt, ckb, cvb, ws + F_YK2, ws + F_YV2);
    k_prep_pw  <<<64,   256, 0, stream>>>(Wq, Wk, Wv, Wo, wt4);
    k_prep_beta<<<1,   1024, 0, stream>>>(Wq, bq, ws + F_STATS, beta0);
    k_proj_mfma<<<dim3(3, 32, 8), 256, 0, stream>>>(xb, ws + F_YK2, ws + F_YV2,
                                                    wt4, bk, bv, ws + F_STATS, beta0,
                                                    qb, kb, vt);
    k_attn     <<<1024, 256, 0, stream>>>(qb, kb, vt, Bb, aob);
    k_out_mfma <<<dim3(32, 8), 256, 0, stream>>>(aob, wot, bo, x, out);
}

// Round 10
// 144.298 us; speedup vs baseline: 1.3625x; 1.3158x over previous
//
#include <hip/hip_runtime.h>
#include <hip/hip_bf16.h>
#include <math.h>

#define B_     8
#define C_     256
#define HW_    1024
#define NTOT   (B_*C_*HW_)     // 2097152
#define HEADS_ 8
#define DK_    32
#define SCALE_ 0.17677669529663687f  // 32^-0.5

// workspace layout (float offsets)
#define F_STATS 0
#define F_PART  16
#define F_YK2   8192
#define F_YV2   (F_YK2 + NTOT)
#define F_XB    (F_YV2 + NTOT)            // NTOT shorts
#define F_WT    (F_XB + NTOT/2)           // conv w: 1179648 shorts; later wt4 + beta0
#define F_QB    (F_WT + 589824)
#define F_KB    (F_QB + NTOT/2)
#define F_VT    (F_KB + NTOT/2)

typedef float f32x4 __attribute__((ext_vector_type(4)));
typedef short short8 __attribute__((ext_vector_type(8)));

__device__ __forceinline__ short bf16s(float f) {
    __hip_bfloat16 h = __float2bfloat16(f);
    return *(short*)&h;
}
__device__ __forceinline__ unsigned pack_bf16(float a, float b) {
    unsigned ua = (unsigned short)bf16s(a);
    unsigned ub = (unsigned short)bf16s(b);
    return ua | (ub << 16);
}
// async global->LDS, 16B per lane; lds dest must be wave-uniform base (+lane*16 by HW)
__device__ __forceinline__ void gload_lds16(const short* g, short* l) {
    __builtin_amdgcn_global_load_lds(
        (const __attribute__((address_space(1))) unsigned*)g,
        (__attribute__((address_space(3))) unsigned*)l, 16, 0, 0);
}

// ---------------- prep: x -> xb bf16 + LN partial sums (fused) --------------
__global__ void k_prep_x(const float* __restrict__ x, short* __restrict__ xb,
                         float* __restrict__ part) {
    __shared__ short t[64 * 258];
    __shared__ float ls[4], ls2[4];
    int b = blockIdx.x >> 4, p0 = (blockIdx.x & 15) << 6;
    int tid = threadIdx.x;
    float s = 0.f, s2 = 0.f;
    for (int i = tid; i < 256 * 64; i += 256) {
        int ci = i >> 6, p = i & 63;
        float v = x[(b * C_ + ci) * HW_ + p0 + p];
        s += v; s2 += v * v;
        t[p * 258 + ci] = bf16s(v);
    }
    for (int o = 32; o; o >>= 1) { s += __shfl_down(s, o); s2 += __shfl_down(s2, o); }
    int wid = tid >> 6, lane = tid & 63;
    if (lane == 0) { ls[wid] = s; ls2[wid] = s2; }
    __syncthreads();
    if (tid == 0) {
        float a = 0.f, bb = 0.f;
        for (int i = 0; i < 4; i++) { a += ls[i]; bb += ls2[i]; }
        part[blockIdx.x * 2] = a; part[blockIdx.x * 2 + 1] = bb;
    }
    for (int i = tid; i < 64 * 256; i += 256) {
        int p = i >> 8, ci = i & 255;
        xb[(b * HW_ + p0 + p) * C_ + ci] = t[p * 258 + ci];
    }
}

__global__ void k_stats(const float* __restrict__ part, float* __restrict__ stats) {
    __shared__ float ls[256], ls2[256];
    float s = 0.f, s2 = 0.f;
    for (int i = threadIdx.x; i < 128; i += 256) { s += part[2 * i]; s2 += part[2 * i + 1]; }
    ls[threadIdx.x] = s; ls2[threadIdx.x] = s2;
    __syncthreads();
    for (int off = 128; off; off >>= 1) {
        if (threadIdx.x < off) { ls[threadIdx.x] += ls[threadIdx.x + off]; ls2[threadIdx.x] += ls2[threadIdx.x + off]; }
        __syncthreads();
    }
    if (threadIdx.x == 0) {
        float m = ls[0] / (float)NTOT;
        float var = ls2[0] / (float)NTOT - m * m;
        stats[0] = m;
        stats[1] = rsqrtf(var + 1e-5f);
    }
}

// ---------------- prep: conv weights -> wt[tap][n(512)][ci] bf16 ------------
__global__ void k_prep_w(const float* __restrict__ wk, const float* __restrict__ wv,
                         short* __restrict__ wt) {
    int idx = blockIdx.x * 256 + threadIdx.x;
    int ci0 = (idx << 2) & 255;
    int rest = idx >> 6;
    int n = rest & 511, tap = rest >> 9;
    const float* src = (n < 256) ? (wk + (n * C_) * 9) : (wv + ((n - 256) * C_) * 9);
    short4 o;
    short* op = (short*)&o;
    for (int u = 0; u < 4; u++)
        op[u] = bf16s(src[(ci0 + u) * 9 + tap]);
    *(short4*)&wt[((tap * 512 + n) * C_) + ci0] = o;
}

// ---------------- prep: proj weights -> wt4[m][e][c] bf16 (transposed) ------
__global__ void k_prep_pw(const float* __restrict__ Wq, const float* __restrict__ Wk,
                          const float* __restrict__ Wv, const float* __restrict__ Wo,
                          short* __restrict__ wt4) {
    __shared__ short t[64 * 66];
    int mi = blockIdx.x >> 4, tl = blockIdx.x & 15;
    int c0 = (tl >> 2) * 64, e0 = (tl & 3) * 64;
    const float* W = mi == 0 ? Wq : mi == 1 ? Wk : mi == 2 ? Wv : Wo;
    int tid = threadIdx.x;
    for (int i = tid; i < 4096; i += 256) {
        int cl = i >> 6, el = i & 63;
        t[cl * 66 + el] = bf16s(W[(c0 + cl) * 256 + e0 + el]);
    }
    __syncthreads();
    for (int i = tid; i < 4096; i += 256) {
        int el = i >> 6, cl = i & 63;
        wt4[mi * 65536 + (e0 + el) * 256 + c0 + cl] = t[cl * 66 + el];
    }
}

// ---------------- prep: beta0[e] = (bq[e] - m*r*colsum(Wq[:,e])) * SCALE ----
__global__ void k_prep_beta(const float* __restrict__ Wq, const float* __restrict__ bq,
                            const float* __restrict__ stats, float* __restrict__ beta0) {
    __shared__ float ps[1024];
    int t = threadIdx.x, e = t & 255, part = t >> 8;
    float s = 0.f;
    for (int c = part * 64; c < part * 64 + 64; c++) s += Wq[c * 256 + e];
    ps[t] = s;
    __syncthreads();
    if (t < 256) {
        float cs = ps[t] + ps[t + 256] + ps[t + 512] + ps[t + 768];
        beta0[t] = (bq[t] - stats[0] * stats[1] * cs) * SCALE_;
    }
}

// ---------------- conv via MFMA implicit GEMM, LDS-staged B -----------------
// grid 512 = b(8) x pt(8: 4 image rows = 128px) x nt(8: 64 cols), nt in LOW bits
// block 512 = 8 waves; wave w: wm=w>>1 (image row), wn=w&1 (32-col half)
__device__ __forceinline__ int a_off(int slot, int chunk) {
    int c = chunk ^ (slot & 3);
    int s = slot ^ ((slot >> 2) & 1);
    return s * 64 + c * 16;
}

__global__ __launch_bounds__(512, 4)
void k_conv_mfma(const short* __restrict__ xb, const short* __restrict__ wt,
                 const float* __restrict__ bk, const float* __restrict__ bv,
                 float* __restrict__ yk2, float* __restrict__ yv2) {
    __shared__ short a_sh[204 * 32];    // 6 rows x 34 cols x 32 ci, swizzled (13 KB)
    __shared__ short b_sh[9 * 2048];    // [tap][256 slots of 8], slot-swizzled (36 KB)
    int bid = blockIdx.x;
    int nt = bid & 7, pt = (bid >> 3) & 7, b = bid >> 6;
    int R0 = pt * 4;
    int tid = threadIdx.x;
    int w = tid >> 6, l = tid & 63;
    int wm = w >> 1, wn = w & 1;
    int col16 = l & 15, kq = l >> 4;

    // A staging: 816 items (204 slots x 4 chunks); thread does items tid, tid+512
    int offs[2], loffs[2];
    #pragma unroll
    for (int it = 0; it < 2; it++) {
        int i = tid + it * 512;
        if (i < 816) {
            int slot = i >> 2, chunk = i & 3;
            int ty = slot / 34, tx = slot - ty * 34;
            int Y = R0 - 1 + ty, X = tx - 1;
            offs[it] = ((unsigned)Y < 32u && (unsigned)X < 32u)
                       ? ((b * HW_ + Y * 32 + X) * C_ + chunk * 8) : -1;
            loffs[it] = a_off(slot, chunk);
        } else { offs[it] = -1; loffs[it] = -1; }
    }

    // B staging: 36 wave-instrs; wave w handles j = w, w+8, ... (lane addr per item)
    // item S = j*64+l -> tap = S>>8, s = S&255; slot s holds (col=s>>2, kq = (s&3)^((col>>1)&3))
    int bgoff[5];
    int nbj = 0;
    #pragma unroll 1
    for (int j = w; j < 36; j += 8) {
        int S = j * 64 + l;
        int tap = S >> 8, s = S & 255;
        int colb = s >> 2, kqs = s & 3;
        int kq2 = kqs ^ ((colb >> 1) & 3);
        bgoff[nbj++] = (tap * 512 + nt * 64 + colb) * C_ + kq2 * 8;
    }

    f32x4 acc[2][2];
    #pragma unroll
    for (int m = 0; m < 2; m++)
        #pragma unroll
        for (int n = 0; n < 2; n++) acc[m][n] = (f32x4)0.f;

    // B read slots for this lane (per nf), constant across taps
    int sr[2];
    #pragma unroll
    for (int nf = 0; nf < 2; nf++) {
        int colb = wn * 32 + nf * 16 + col16;
        sr[nf] = (colb << 2) | (kq ^ ((colb >> 1) & 3));
    }

    // ---- stage step 0 ----
    {
        short8 sv[2];
        #pragma unroll
        for (int it = 0; it < 2; it++)
            sv[it] = (offs[it] >= 0) ? *(const short8*)(xb + offs[it]) : (short8)0;
        int jj = 0;
        #pragma unroll 1
        for (int j = w; j < 36; j += 8, jj++)
            gload_lds16(wt + bgoff[jj], b_sh + j * 512);
        #pragma unroll
        for (int it = 0; it < 2; it++)
            if (loffs[it] >= 0) *(short8*)((char*)a_sh + loffs[it]) = sv[it];
    }
    __syncthreads();   // compiler drains vmcnt+lgkmcnt here

    #pragma unroll 1
    for (int step = 0; step < 8; step++) {
        // compute from LDS: 9 taps x (2 A-frag ds_read + 2 B-frag ds_read + 4 MFMA)
        const char* ab = (const char*)a_sh;
        const char* bbp = (const char*)b_sh;
        #pragma unroll
        for (int tap = 0; tap < 9; tap++) {
            const int dyi = tap / 3, dxi = tap % 3;
            short8 af[2], bf[2];
            #pragma unroll
            for (int mf = 0; mf < 2; mf++) {
                int slot = (wm + dyi) * 34 + mf * 16 + col16 + dxi;
                af[mf] = *(const short8*)(ab + a_off(slot, kq));
            }
            #pragma unroll
            for (int nf = 0; nf < 2; nf++)
                bf[nf] = *(const short8*)(bbp + tap * 4096 + sr[nf] * 16);
            #pragma unroll
            for (int mf = 0; mf < 2; mf++)
                #pragma unroll
                for (int nf = 0; nf < 2; nf++)
                    acc[mf][nf] = __builtin_amdgcn_mfma_f32_16x16x32_bf16(af[mf], bf[nf], acc[mf][nf], 0, 0, 0);
        }
        if (step < 7) {
            int ci0n = step * 32 + 32;
            __syncthreads();   // compute done, LDS reusable
            short8 sv[2];
            #pragma unroll
            for (int it = 0; it < 2; it++)
                sv[it] = (offs[it] >= 0) ? *(const short8*)(xb + offs[it] + ci0n) : (short8)0;
            int jj = 0;
            #pragma unroll 1
            for (int j = w; j < 36; j += 8, jj++)
                gload_lds16(wt + bgoff[jj] + ci0n, b_sh + j * 512);
            #pragma unroll
            for (int it = 0; it < 2; it++)
                if (loffs[it] >= 0) *(short8*)((char*)a_sh + loffs[it]) = sv[it];
            __syncthreads();   // staging visible
        }
    }

    const bool isv = (nt >= 4);
    float* dst = isv ? yv2 : yk2;
    const float* bias = isv ? bv : bk;
    int cbase = (nt & 3) * 64 + wn * 32 + col16;
    #pragma unroll
    for (int nf = 0; nf < 2; nf++) {
        int co = cbase + nf * 16;
        float bi = bias[co];
        #pragma unroll
        for (int mf = 0; mf < 2; mf++) {
            #pragma unroll
            for (int r = 0; r < 4; r++) {
                int pixel = pt * 128 + wm * 32 + mf * 16 + kq * 4 + r;
                dst[(b * HW_ + pixel) * C_ + co] = acc[mf][nf][r] + bi;
            }
        }
    }
}

// ---------------- stage 3: projections via MFMA -----------------------------
__global__ void k_proj_mfma(const short* __restrict__ xb,
                            const float* __restrict__ yk2, const float* __restrict__ yv2,
                            const short* __restrict__ wt4,
                            const float* __restrict__ bkp, const float* __restrict__ bvp,
                            const float* __restrict__ stats, const float* __restrict__ beta0,
                            short* __restrict__ qb, short* __restrict__ kb,
                            short* __restrict__ vt) {
    __shared__ char smem[17408];
    int pj = blockIdx.x, pt = blockIdx.y, b = blockIdx.z;
    int p0 = pt * 32;
    int tid = threadIdx.x, w = tid >> 6, l = tid & 63;
    int c16 = l & 15, kq = l >> 4;

    if (pj == 0) {
        #pragma unroll
        for (int it = 0; it < 4; it++) {
            int i = it * 256 + tid;
            int slab = i >> 7, rem = i & 127, slot = rem >> 2, chunk = rem & 3;
            short8 v = *(const short8*)(xb + ((b * HW_ + p0 + slot) * C_ + slab * 32 + chunk * 8));
            *(short8*)(smem + slab * 2048 + a_off(slot, chunk)) = v;
        }
    } else {
        const float* src = (pj == 1) ? yk2 : yv2;
        #pragma unroll
        for (int it = 0; it < 4; it++) {
            int i = it * 256 + tid;
            int slab = i >> 7, rem = i & 127, slot = rem >> 2, chunk = rem & 3;
            const float* sp = src + (b * HW_ + p0 + slot) * C_ + slab * 32 + chunk * 8;
            float4 f0 = *(const float4*)sp;
            float4 f1 = *(const float4*)(sp + 4);
            short8 v;
            v[0] = bf16s(f0.x); v[1] = bf16s(f0.y); v[2] = bf16s(f0.z); v[3] = bf16s(f0.w);
            v[4] = bf16s(f1.x); v[5] = bf16s(f1.y); v[6] = bf16s(f1.z); v[7] = bf16s(f1.w);
            *(short8*)(smem + slab * 2048 + a_off(slot, chunk)) = v;
        }
    }
    __syncthreads();

    const short* wt_p = wt4 + pj * 65536;
    f32x4 acc[2][4];
    #pragma unroll
    for (int m = 0; m < 2; m++)
        #pragma unroll
        for (int n = 0; n < 4; n++) acc[m][n] = (f32x4)0.f;

    for (int s = 0; s < 8; s++) {
        short8 af[2], bf[4];
        #pragma unroll
        for (int mf = 0; mf < 2; mf++)
            af[mf] = *(const short8*)(smem + s * 2048 + a_off(mf * 16 + c16, kq));
        #pragma unroll
        for (int nf = 0; nf < 4; nf++)
            bf[nf] = *(const short8*)(wt_p + (w * 64 + nf * 16 + c16) * 256 + s * 32 + kq * 8);
        #pragma unroll
        for (int mf = 0; mf < 2; mf++)
            #pragma unroll
            for (int nf = 0; nf < 4; nf++)
                acc[mf][nf] = __builtin_amdgcn_mfma_f32_16x16x32_bf16(af[mf], bf[nf], acc[mf][nf], 0, 0, 0);
    }

    float alpha = (pj == 0) ? stats[1] * SCALE_ : 1.f;
    float beta[4];
    #pragma unroll
    for (int nf = 0; nf < 4; nf++) {
        int e = w * 64 + nf * 16 + c16;
        beta[nf] = (pj == 0) ? beta0[e] : (pj == 1 ? bkp[e] : bvp[e]);
    }
    __syncthreads();

    short* rp = (short*)smem + w * 2176;
    if (pj < 2) {
        #pragma unroll
        for (int mf = 0; mf < 2; mf++)
            #pragma unroll
            for (int nf = 0; nf < 4; nf++)
                #pragma unroll
                for (int rg = 0; rg < 4; rg++) {
                    int px = mf * 16 + kq * 4 + rg, el = nf * 16 + c16;
                    rp[px * 66 + el] = bf16s(alpha * acc[mf][nf][rg] + beta[nf]);
                }
        __syncthreads();
        short* dst = (pj == 0) ? qb : kb;
        #pragma unroll
        for (int j = 0; j < 4; j++) {
            int px = j * 8 + (l >> 3), el = (l & 7) * 8;
            short8 v = *(const short8*)(rp + px * 66 + el);
            int e = w * 64 + el, h = e >> 5, d = e & 31;
            *(short8*)(dst + ((b * 8 + h) * HW_ + p0 + px) * DK_ + d) = v;
        }
    } else {
        #pragma unroll
        for (int mf = 0; mf < 2; mf++)
            #pragma unroll
            for (int nf = 0; nf < 4; nf++)
                #pragma unroll
                for (int rg = 0; rg < 4; rg++) {
                    int px = mf * 16 + kq * 4 + rg, el = nf * 16 + c16;
                    rp[el * 34 + px] = bf16s(acc[mf][nf][rg] + beta[nf]);
                }
        __syncthreads();
        #pragma unroll
        for (int j = 0; j < 4; j++) {
            int el = j * 16 + (l >> 2), px = (l & 3) * 8;
            short8 v = *(const short8*)(rp + el * 34 + px);
            int e = w * 64 + el, h = e >> 5, d = e & 31;
            *(short8*)(vt + ((b * 8 + h) * DK_ + d) * HW_ + p0 + px) = v;
        }
    }
}

// ---------------- stage 4: attention (MFMA flash, swapped QK^T) -------------
__global__ void k_attn(const short* __restrict__ qb, const short* __restrict__ kb,
                       const short* __restrict__ vt, const float* __restrict__ Bb,
                       short* __restrict__ ao) {
    __shared__ __align__(16) short Qs[64 * 32];
    __shared__ __align__(16) short Ks[64 * 32];
    __shared__ __align__(16) short Vs[32 * 64];
    __shared__ __align__(16) short Ps[4][16 * 64];
    int bid = blockIdx.x;
    int h = bid & 7, b = (bid >> 3) & 7, qt = bid >> 6;
    int bh = b * HEADS_ + h;
    int tid = threadIdx.x, w = tid >> 6, l = tid & 63;
    int g = l >> 4, c16 = l & 15;

    *(short8*)(Qs + tid * 8) = *(const short8*)(qb + (bh * HW_ + qt * 64) * DK_ + tid * 8);

    const float* Brow = Bb + (h * HW_ + qt * 64 + w * 16 + c16) * HW_;
    float m_run = -1e30f, l_run = 0.f;
    f32x4 ot[2];
    ot[0] = (f32x4)0.f; ot[1] = (f32x4)0.f;
    char* pbase = (char*)&Ps[w][0];
    int vrow = tid >> 3, vch = tid & 7;

    for (int kv0 = 0; kv0 < HW_; kv0 += 64) {
        __syncthreads();
        *(short8*)(Ks + tid * 8) = *(const short8*)(kb + (bh * HW_ + kv0) * DK_ + tid * 8);
        {
            short8 v = *(const short8*)(vt + (bh * DK_ + vrow) * HW_ + kv0 + vch * 8);
            *(short8*)((char*)Vs + vrow * 128 + ((vch * 16) ^ ((vrow & 7) << 4))) = v;
        }
        __syncthreads();

        short8 qf = *(const short8*)(Qs + (w * 16 + c16) * DK_ + g * 8);
        f32x4 st[4];
        #pragma unroll
        for (int mt = 0; mt < 4; mt++) {
            float4 bi = *(const float4*)(Brow + kv0 + mt * 16 + g * 4);
            f32x4 acc; acc[0] = bi.x; acc[1] = bi.y; acc[2] = bi.z; acc[3] = bi.w;
            short8 kf = *(const short8*)(Ks + (mt * 16 + c16) * DK_ + g * 8);
            st[mt] = __builtin_amdgcn_mfma_f32_16x16x32_bf16(kf, qf, acc, 0, 0, 0);
        }

        float mx = m_run;
        #pragma unroll
        for (int mt = 0; mt < 4; mt++)
            #pragma unroll
            for (int rg = 0; rg < 4; rg++) mx = fmaxf(mx, st[mt][rg]);
        mx = fmaxf(mx, __shfl_xor(mx, 16));
        mx = fmaxf(mx, __shfl_xor(mx, 32));
        float f = __expf(m_run - mx);
        m_run = mx;
        float s = 0.f;
        #pragma unroll
        for (int mt = 0; mt < 4; mt++)
            #pragma unroll
            for (int rg = 0; rg < 4; rg++) {
                float e_ = __expf(st[mt][rg] - mx);
                st[mt][rg] = e_;
                s += e_;
            }
        s += __shfl_xor(s, 16);
        s += __shfl_xor(s, 32);
        l_run = l_run * f + s;

        int fv = __float_as_int(f);
        #pragma unroll
        for (int rg = 0; rg < 4; rg++) {
            float fr = __int_as_float(__builtin_amdgcn_ds_bpermute((g * 4 + rg) << 2, fv));
            ot[0][rg] *= fr;
            ot[1][rg] *= fr;
        }

        #pragma unroll
        for (int mt = 0; mt < 4; mt++) {
            unsigned lo = pack_bf16(st[mt][0], st[mt][1]);
            unsigned hi = pack_bf16(st[mt][2], st[mt][3]);
            unsigned long long pr = (unsigned long long)lo | ((unsigned long long)hi << 32);
            *(unsigned long long*)(pbase + c16 * 128 + ((mt * 32 + g * 8) ^ ((c16 & 7) << 4))) = pr;
        }
        #pragma unroll
        for (int kt = 0; kt < 2; kt++) {
            short8 pf = *(const short8*)(pbase + c16 * 128 + ((kt * 64 + g * 16) ^ ((c16 & 7) << 4)));
            #pragma unroll
            for (int nt = 0; nt < 2; nt++) {
                short8 vf = *(const short8*)((char*)Vs + (c16 + 16 * nt) * 128 + ((kt * 64 + g * 16) ^ ((c16 & 7) << 4)));
                ot[nt] = __builtin_amdgcn_mfma_f32_16x16x32_bf16(pf, vf, ot[nt], 0, 0, 0);
            }
        }
    }

    float linv = 1.f / l_run;
    int lrv = __float_as_int(linv);
    #pragma unroll
    for (int rg = 0; rg < 4; rg++) {
        float li = __int_as_float(__builtin_amdgcn_ds_bpermute((g * 4 + rg) << 2, lrv));
        int qg = qt * 64 + w * 16 + g * 4 + rg;
        #pragma unroll
        for (int nt = 0; nt < 2; nt++)
            ao[(b * HW_ + qg) * C_ + h * DK_ + nt * 16 + c16] = bf16s(ot[nt][rg] * li);
    }
}

// ---------------- stage 5: output projection via MFMA + residual ------------
__global__ void k_out_mfma(const short* __restrict__ aob, const short* __restrict__ wot,
                           const float* __restrict__ bo, const float* __restrict__ x,
                           float* __restrict__ out) {
    __shared__ char smem[16384];
    int pt = blockIdx.x, b = blockIdx.y;
    int p0 = pt * 32;
    int tid = threadIdx.x, w = tid >> 6, l = tid & 63;
    int c16 = l & 15, kq = l >> 4;

    #pragma unroll
    for (int it = 0; it < 4; it++) {
        int i = it * 256 + tid;
        int slab = i >> 7, rem = i & 127, slot = rem >> 2, chunk = rem & 3;
        short8 v = *(const short8*)(aob + ((b * HW_ + p0 + slot) * C_ + slab * 32 + chunk * 8));
        *(short8*)(smem + slab * 2048 + a_off(slot, chunk)) = v;
    }
    __syncthreads();

    f32x4 acc[2][4];
    #pragma unroll
    for (int m = 0; m < 2; m++)
        #pragma unroll
        for (int n = 0; n < 4; n++) acc[m][n] = (f32x4)0.f;

    for (int s = 0; s < 8; s++) {
        short8 af[2], bf[4];
        #pragma unroll
        for (int mf = 0; mf < 2; mf++)
            af[mf] = *(const short8*)(smem + s * 2048 + a_off(mf * 16 + c16, kq));
        #pragma unroll
        for (int nf = 0; nf < 4; nf++)
            bf[nf] = *(const short8*)(wot + (w * 64 + nf * 16 + c16) * 256 + s * 32 + kq * 8);
        #pragma unroll
        for (int mf = 0; mf < 2; mf++)
            #pragma unroll
            for (int nf = 0; nf < 4; nf++)
                acc[mf][nf] = __builtin_amdgcn_mfma_f32_16x16x32_bf16(af[mf], bf[nf], acc[mf][nf], 0, 0, 0);
    }

    #pragma unroll
    for (int nf = 0; nf < 4; nf++) {
        int e = w * 64 + nf * 16 + c16;
        float bov = bo[e];
        #pragma unroll
        for (int mf = 0; mf < 2; mf++) {
            #pragma unroll
            for (int rg = 0; rg < 4; rg++) {
                int px = mf * 16 + kq * 4 + rg;
                int idx = b * (C_ * HW_) + (p0 + px) * 256 + e;
                out[idx] = acc[mf][nf][rg] + bov + x[idx];
            }
        }
    }
}

extern "C" void kernel_launch(void* const* d_in, const int* in_sizes, int n_in,
                              void* d_out, int out_size, void* d_ws, size_t ws_size,
                              hipStream_t stream) {
    const float* x   = (const float*)d_in[0];
    const float* Wq  = (const float*)d_in[1];
    const float* bq  = (const float*)d_in[2];
    const float* ckw = (const float*)d_in[3];
    const float* ckb = (const float*)d_in[4];
    const float* Wk  = (const float*)d_in[5];
    const float* bk  = (const float*)d_in[6];
    const float* cvw = (const float*)d_in[7];
    const float* cvb = (const float*)d_in[8];
    const float* Wv  = (const float*)d_in[9];
    const float* bv  = (const float*)d_in[10];
    const float* Wo  = (const float*)d_in[11];
    const float* bo  = (const float*)d_in[12];
    const float* Bb  = (const float*)d_in[13];
    float* ws  = (float*)d_ws;
    float* out = (float*)d_out;

    short* xb      = (short*)(ws + F_XB);
    short* wt      = (short*)(ws + F_WT);
    short* wt4     = (short*)(ws + F_WT);
    float* beta0   = ws + F_WT + 131072;
    short* qb      = (short*)(ws + F_QB);
    short* kb      = (short*)(ws + F_KB);
    short* vt      = (short*)(ws + F_VT);
    short* aob     = (short*)(ws + F_YK2);
    short* wot     = wt4 + 3 * 65536;

    k_prep_x   <<<128,  256, 0, stream>>>(x, xb, ws + F_PART);
    k_stats    <<<1,    256, 0, stream>>>(ws + F_PART, ws + F_STATS);
    k_prep_w   <<<1152, 256, 0, stream>>>(ckw, cvw, wt);
    k_conv_mfma<<<512,  512, 0, stream>>>(xb, wt, ckb, cvb, ws + F_YK2, ws + F_YV2);
    k_prep_pw  <<<64,   256, 0, stream>>>(Wq, Wk, Wv, Wo, wt4);
    k_prep_beta<<<1,   1024, 0, stream>>>(Wq, bq, ws + F_STATS, beta0);
    k_proj_mfma<<<dim3(3, 32, 8), 256, 0, stream>>>(xb, ws + F_YK2, ws + F_YV2,
                                                    wt4, bk, bv, ws + F_STATS, beta0,
                                                    qb, kb, vt);
    k_attn     <<<1024, 256, 0, stream>>>(qb, kb, vt, Bb, aob);
    k_out_mfma <<<dim3(32, 8), 256, 0, stream>>>(aob, wot, bo, x, out);
}